// Round 3
// baseline (1263.301 us; speedup 1.0000x reference)
//
#include <hip/hip_runtime.h>
#include <stdint.h>

typedef __attribute__((ext_vector_type(4))) float f32x4;
typedef __attribute__((ext_vector_type(4))) unsigned short u16x4;
typedef __attribute__((ext_vector_type(8))) unsigned short u16x8;
typedef __attribute__((ext_vector_type(8))) short s16x8;

#define NH   32
#define NKV  8
#define HD   128
#define SEQ  2048
#define MTOK 4096   // BATCH*SEQ

__device__ __forceinline__ float b2f(unsigned short u) {
  union { float f; unsigned int i; } v; v.i = ((unsigned int)u) << 16; return v.f;
}
__device__ __forceinline__ unsigned short f2b(float f) {
  unsigned int i = __float_as_uint(f);
  return (unsigned short)((i + 0x7fffu + ((i >> 16) & 1u)) >> 16);
}

// ---------------- elementwise f32 -> bf16 ----------------
__global__ void convert_f32_bf16(const float* __restrict__ in,
                                 unsigned short* __restrict__ out, int n4) {
  int i = blockIdx.x * 256 + threadIdx.x;
  if (i >= n4) return;
  f32x4 v = *(const f32x4*)(in + (size_t)i * 4);
  u16x4 r;
  r.x = f2b(v.x); r.y = f2b(v.y); r.z = f2b(v.z); r.w = f2b(v.w);
  *(u16x4*)(out + (size_t)i * 4) = r;
}

// ---------------- transpose + convert: W (K=4096 x N) f32 -> WT (N x 4096) bf16 ----
__global__ void tconv(const float* __restrict__ W, unsigned short* __restrict__ WT, int N) {
  __shared__ float tile[32][33];
  int k0 = blockIdx.x * 32, n0 = blockIdx.y * 32;
  int t = threadIdx.x;
  int r = t >> 3;          // 0..31
  int c = (t & 7) * 4;     // 0..28
  f32x4 v = *(const f32x4*)&W[(size_t)(k0 + r) * N + n0 + c];
  tile[r][c + 0] = v.x; tile[r][c + 1] = v.y; tile[r][c + 2] = v.z; tile[r][c + 3] = v.w;
  __syncthreads();
  u16x4 o;
  o.x = f2b(tile[c + 0][r]); o.y = f2b(tile[c + 1][r]);
  o.z = f2b(tile[c + 2][r]); o.w = f2b(tile[c + 3][r]);
  *(u16x4*)&WT[(size_t)(n0 + r) * 4096 + k0 + c] = o;
}

// ---------------- V transpose: vb (b,s,kvh,d) -> vtb (b,kvh,d,s) bf16 -------------
__global__ void vtrans(const unsigned short* __restrict__ vb, unsigned short* __restrict__ vtb) {
  __shared__ unsigned short tile[32][36];
  int s0 = blockIdx.x * 32, d0 = blockIdx.y * 32;
  int bkv = blockIdx.z; int b = bkv >> 3, kvh = bkv & 7;
  int t = threadIdx.x;
  int r = t >> 3, c = (t & 7) * 4;
  u16x4 v = *(const u16x4*)&vb[((size_t)(b * SEQ + s0 + r) * NKV + kvh) * HD + d0 + c];
  tile[r][c + 0] = v.x; tile[r][c + 1] = v.y; tile[r][c + 2] = v.z; tile[r][c + 3] = v.w;
  __syncthreads();
  u16x4 o;
  o.x = tile[c + 0][r]; o.y = tile[c + 1][r]; o.z = tile[c + 2][r]; o.w = tile[c + 3][r];
  *(u16x4*)&vtb[((size_t)(b * NKV + kvh) * HD + d0 + r) * SEQ + s0 + c] = o;
}

// ---------------- RoPE in-place on bf16 (b,s,nh,128) -------------------------------
__global__ void rope_k(unsigned short* __restrict__ x, const float* __restrict__ cs,
                       const float* __restrict__ sn, int nhShift, int total) {
  int i = blockIdx.x * 256 + threadIdx.x;
  if (i >= total) return;
  int g = i & 15;                    // 16 groups of 8 elements within HD=128
  int rem = i >> 4;
  int h = rem & ((1 << nhShift) - 1);
  int sb = rem >> nhShift;           // b*SEQ + s
  int s = sb & (SEQ - 1);
  size_t base = (((size_t)sb << nhShift) + h) * HD + g * 8;
  u16x8 v = *(u16x8*)(x + base);
  f32x4 c = *(const f32x4*)(cs + s * 64 + g * 4);
  f32x4 sv = *(const f32x4*)(sn + s * 64 + g * 4);
#pragma unroll
  for (int j = 0; j < 4; ++j) {
    float re = b2f(v[2 * j]), im = b2f(v[2 * j + 1]);
    float cj = c[j], sj = sv[j];
    v[2 * j]     = f2b(re * cj - im * sj);
    v[2 * j + 1] = f2b(re * sj + im * cj);
  }
  *(u16x8*)(x + base) = v;
}

// ---------------- GEMM: C[M,N] = A[M,K](bf16) * BT[N,K](bf16)^T --------------------
// 128x128 tile, BK=64, 256 threads (4 waves, 2x2), 16x16x32 bf16 MFMA (m97 structure)
template <typename OutT>
__global__ __launch_bounds__(256, 2)
void gemm_bt(const unsigned short* __restrict__ A, const unsigned short* __restrict__ BT,
             OutT* __restrict__ C, int M, int N, int K) {
  __shared__ __align__(16) unsigned short As[128 * 64];
  __shared__ __align__(16) unsigned short Bs[128 * 64];
  const int t = threadIdx.x;
  const int lane = t & 63;
  const int w = t >> 6;
  const int l15 = lane & 15, l4 = lane >> 4;
  const int wm = w >> 1, wn = w & 1;
  const int m0 = blockIdx.x * 128, n0 = blockIdx.y * 128;

  f32x4 acc[4][4];
#pragma unroll
  for (int i = 0; i < 4; ++i)
#pragma unroll
    for (int j = 0; j < 4; ++j) acc[i][j] = (f32x4)(0.0f);

  for (int k0 = 0; k0 < K; k0 += 64) {
#pragma unroll
    for (int p = 0; p < 4; ++p) {
      int cb = p * 256 + w * 64;     // wave-uniform chunk base
      int c = cb + lane;
      int row = c >> 3, co = (c & 7) * 8;
      const unsigned short* srcA = A + (size_t)(m0 + row) * K + k0 + co;
      const unsigned short* srcB = BT + (size_t)(n0 + row) * K + k0 + co;
      __builtin_amdgcn_global_load_lds((const __attribute__((address_space(1))) void*)srcA,
                                       (__attribute__((address_space(3))) void*)(As + cb * 8),
                                       16, 0, 0);
      __builtin_amdgcn_global_load_lds((const __attribute__((address_space(1))) void*)srcB,
                                       (__attribute__((address_space(3))) void*)(Bs + cb * 8),
                                       16, 0, 0);
    }
    __syncthreads();
    s16x8 af[4][2], bfr[4][2];
#pragma unroll
    for (int mi = 0; mi < 4; ++mi)
#pragma unroll
      for (int kk = 0; kk < 2; ++kk)
        af[mi][kk] = *(const s16x8*)&As[(wm * 64 + mi * 16 + l15) * 64 + kk * 32 + l4 * 8];
#pragma unroll
    for (int ni = 0; ni < 4; ++ni)
#pragma unroll
      for (int kk = 0; kk < 2; ++kk)
        bfr[ni][kk] = *(const s16x8*)&Bs[(wn * 64 + ni * 16 + l15) * 64 + kk * 32 + l4 * 8];
#pragma unroll
    for (int kk = 0; kk < 2; ++kk)
#pragma unroll
      for (int mi = 0; mi < 4; ++mi)
#pragma unroll
        for (int ni = 0; ni < 4; ++ni)
          acc[mi][ni] = __builtin_amdgcn_mfma_f32_16x16x32_bf16(af[mi][kk], bfr[ni][kk],
                                                                acc[mi][ni], 0, 0, 0);
    __syncthreads();
  }
#pragma unroll
  for (int mi = 0; mi < 4; ++mi)
#pragma unroll
    for (int ni = 0; ni < 4; ++ni) {
      int col = n0 + wn * 64 + ni * 16 + l15;
#pragma unroll
      for (int r = 0; r < 4; ++r) {
        int row = m0 + wm * 64 + mi * 16 + l4 * 4 + r;
        if constexpr (sizeof(OutT) == 2)
          C[(size_t)row * N + col] = f2b(acc[mi][ni][r]);
        else
          C[(size_t)row * N + col] = acc[mi][ni][r];
      }
    }
}

// ---------------- Flash attention, causal, GQA 4:1 ---------------------------------
// block = 256 threads (4 waves). Block handles 64 q rows of one (b,h); wave w owns 16.
// KV tiles of 64 keys staged in LDS (padded rows: Ks stride 272B = 4 banks mod 32,
// Vs/Ps stride 144B = 4 banks mod 32 -> 2 lanes/bank = conflict-free per m136).
__global__ __launch_bounds__(256, 2)
void attn_kernel(const unsigned short* __restrict__ qb, const unsigned short* __restrict__ kb,
                 const unsigned short* __restrict__ vtb, unsigned short* __restrict__ ab) {
  __shared__ __align__(16) unsigned short Ks[64 * 136];   // [key][d] pad +8
  __shared__ __align__(16) unsigned short Vs[128 * 72];   // [d][key] pad +8
  __shared__ __align__(16) unsigned short Ps[4 * 16 * 72];// per-wave [qrow][key] pad +8
  const int bx = (int)blockIdx.x;
  const int qt = bx & 31;
  const int h = (bx >> 5) & 31;
  const int b = bx >> 10;
  const int kvh = h >> 2;
  const int t = threadIdx.x, lane = t & 63, w = t >> 6;
  const int l15 = lane & 15, l4 = lane >> 4;
  const int q0 = qt * 64;
  const float SCALE = 0.08838834764831845f;  // 1/sqrt(128)

  // hoist Q fragments (A-operand: row = l15, k = kk*32 + l4*8 + j)
  size_t qoff = ((size_t)(b * SEQ + q0 + w * 16 + l15) * NH + h) * HD;
  s16x8 qf[4];
#pragma unroll
  for (int kk = 0; kk < 4; ++kk) qf[kk] = *(const s16x8*)(qb + qoff + kk * 32 + l4 * 8);

  f32x4 accO[8];
#pragma unroll
  for (int n = 0; n < 8; ++n) accO[n] = (f32x4)(0.0f);
  float mrow[4] = {-1e30f, -1e30f, -1e30f, -1e30f};
  float lrow[4] = {0.f, 0.f, 0.f, 0.f};
  unsigned short* Pw = Ps + w * 16 * 72;

  for (int kt = 0; kt <= qt; ++kt) {
    const int k0 = kt * 64;
    // stage K tile [64][128] and V^T tile [128][64] (reg-staged: padded LDS rows)
#pragma unroll
    for (int p = 0; p < 4; ++p) {
      int c = p * 256 + t;
      {
        int row = c >> 4, co = (c & 15) * 8;
        u16x8 v = *(const u16x8*)(kb + ((size_t)(b * SEQ + k0 + row) * NKV + kvh) * HD + co);
        *(u16x8*)&Ks[row * 136 + co] = v;
      }
      {
        int row = c >> 3, co = (c & 7) * 8;
        u16x8 v = *(const u16x8*)(vtb + ((size_t)(b * NKV + kvh) * HD + row) * SEQ + k0 + co);
        *(u16x8*)&Vs[row * 72 + co] = v;
      }
    }
    __syncthreads();

    // S = Q K^T : 4 key-groups of 16, K-dim 128 = 4 MFMAs each
    f32x4 sc[4];
#pragma unroll
    for (int g = 0; g < 4; ++g) sc[g] = (f32x4)(0.0f);
#pragma unroll
    for (int g = 0; g < 4; ++g)
#pragma unroll
      for (int kk = 0; kk < 4; ++kk) {
        s16x8 kf = *(const s16x8*)&Ks[(g * 16 + l15) * 136 + kk * 32 + l4 * 8];
        sc[g] = __builtin_amdgcn_mfma_f32_16x16x32_bf16(qf[kk], kf, sc[g], 0, 0, 0);
      }
    // scale + causal mask (only diagonal tile needs mask)
    if (kt == qt) {
#pragma unroll
      for (int g = 0; g < 4; ++g)
#pragma unroll
        for (int r = 0; r < 4; ++r) {
          int key = g * 16 + l15;
          int qr = w * 16 + l4 * 4 + r;
          float v = sc[g][r] * SCALE;
          sc[g][r] = (key <= qr) ? v : -1e30f;
        }
    } else {
#pragma unroll
      for (int g = 0; g < 4; ++g)
#pragma unroll
        for (int r = 0; r < 4; ++r) sc[g][r] *= SCALE;
    }
    // online softmax: row stats via 16-lane butterfly (C row = l4*4+r)
    float resc[4], newm[4];
#pragma unroll
    for (int r = 0; r < 4; ++r) {
      float tm = fmaxf(fmaxf(sc[0][r], sc[1][r]), fmaxf(sc[2][r], sc[3][r]));
      tm = fmaxf(tm, __shfl_xor(tm, 1));
      tm = fmaxf(tm, __shfl_xor(tm, 2));
      tm = fmaxf(tm, __shfl_xor(tm, 4));
      tm = fmaxf(tm, __shfl_xor(tm, 8));
      newm[r] = fmaxf(mrow[r], tm);
      resc[r] = __expf(mrow[r] - newm[r]);
      mrow[r] = newm[r];
    }
    float pv[4][4];
#pragma unroll
    for (int g = 0; g < 4; ++g)
#pragma unroll
      for (int r = 0; r < 4; ++r) pv[g][r] = __expf(sc[g][r] - newm[r]);
#pragma unroll
    for (int r = 0; r < 4; ++r) {
      float s = pv[0][r] + pv[1][r] + pv[2][r] + pv[3][r];
      s += __shfl_xor(s, 1);
      s += __shfl_xor(s, 2);
      s += __shfl_xor(s, 4);
      s += __shfl_xor(s, 8);
      lrow[r] = lrow[r] * resc[r] + s;
    }
    // P -> wave-private LDS (bf16), O rescale
#pragma unroll
    for (int g = 0; g < 4; ++g)
#pragma unroll
      for (int r = 0; r < 4; ++r) Pw[(l4 * 4 + r) * 72 + g * 16 + l15] = f2b(pv[g][r]);
#pragma unroll
    for (int n = 0; n < 8; ++n)
#pragma unroll
      for (int r = 0; r < 4; ++r) accO[n][r] *= resc[r];
    // O += P V : A = P (row=l15, k=key), B = V^T tile (col=l15 -> d)
    s16x8 pf[2];
    pf[0] = *(const s16x8*)&Pw[l15 * 72 + l4 * 8];
    pf[1] = *(const s16x8*)&Pw[l15 * 72 + 32 + l4 * 8];
#pragma unroll
    for (int n = 0; n < 8; ++n)
#pragma unroll
      for (int kk = 0; kk < 2; ++kk) {
        s16x8 vf = *(const s16x8*)&Vs[(n * 16 + l15) * 72 + kk * 32 + l4 * 8];
        accO[n] = __builtin_amdgcn_mfma_f32_16x16x32_bf16(pf[kk], vf, accO[n], 0, 0, 0);
      }
    __syncthreads();
  }
  // epilogue: normalize and store bf16
  float inv[4];
#pragma unroll
  for (int r = 0; r < 4; ++r) inv[r] = 1.0f / lrow[r];
#pragma unroll
  for (int n = 0; n < 8; ++n)
#pragma unroll
    for (int r = 0; r < 4; ++r) {
      int s = q0 + w * 16 + l4 * 4 + r;
      ab[((size_t)(b * SEQ + s) * NH + h) * HD + n * 16 + l15] = f2b(accO[n][r] * inv[r]);
    }
}

// ---------------- launch -----------------------------------------------------------
extern "C" void kernel_launch(void* const* d_in, const int* in_sizes, int n_in,
                              void* d_out, int out_size, void* d_ws, size_t ws_size,
                              hipStream_t stream) {
  const float* x = (const float*)d_in[0];
  const float* wq = (const float*)d_in[1];
  const float* wk = (const float*)d_in[2];
  const float* wv = (const float*)d_in[3];
  const float* wo = (const float*)d_in[4];
  const float* fcos = (const float*)d_in[7];
  const float* fsin = (const float*)d_in[8];
  float* out = (float*)d_out;

  unsigned short* ws = (unsigned short*)d_ws;
  unsigned short* xb  = ws;                    // 16.78M el
  unsigned short* wqT = ws + 16777216;         // 16.78M
  unsigned short* wkT = ws + 33554432;         // 4.19M
  unsigned short* wvT = ws + 37748736;         // 4.19M
  unsigned short* woT = ws + 41943040;         // 16.78M
  unsigned short* qb  = ws + 58720256;         // 16.78M
  unsigned short* kb  = ws + 75497472;         // 4.19M
  unsigned short* vb  = ws + 79691776;         // 4.19M
  unsigned short* vtb = ws + 83886080;         // 4.19M
  unsigned short* ab  = ws + 88080384;         // 16.78M  (total ~200 MB)

  convert_f32_bf16<<<(4194304 + 255) / 256, 256, 0, stream>>>(x, xb, 4194304);
  tconv<<<dim3(128, 128), 256, 0, stream>>>(wq, wqT, 4096);
  tconv<<<dim3(128, 32), 256, 0, stream>>>(wk, wkT, 1024);
  tconv<<<dim3(128, 32), 256, 0, stream>>>(wv, wvT, 1024);
  tconv<<<dim3(128, 128), 256, 0, stream>>>(wo, woT, 4096);

  gemm_bt<unsigned short><<<dim3(32, 32), 256, 0, stream>>>(xb, wqT, qb, MTOK, 4096, 4096);
  gemm_bt<unsigned short><<<dim3(32, 8), 256, 0, stream>>>(xb, wkT, kb, MTOK, 1024, 4096);
  gemm_bt<unsigned short><<<dim3(32, 8), 256, 0, stream>>>(xb, wvT, vb, MTOK, 1024, 4096);

  rope_k<<<(2097152 + 255) / 256, 256, 0, stream>>>(qb, fcos, fsin, 5, 2097152);
  rope_k<<<(524288 + 255) / 256, 256, 0, stream>>>(kb, fcos, fsin, 3, 524288);

  vtrans<<<dim3(64, 4, 16), 256, 0, stream>>>(vb, vtb);

  attn_kernel<<<2048, 256, 0, stream>>>(qb, kb, vtb, ab);

  gemm_bt<float><<<dim3(32, 32), 256, 0, stream>>>(ab, woT, out, MTOK, 4096, 4096);
}

// Round 4
// 1030.567 us; speedup vs baseline: 1.2258x; 1.2258x over previous
//
#include <hip/hip_runtime.h>
#include <stdint.h>

typedef __attribute__((ext_vector_type(4))) float f32x4;
typedef __attribute__((ext_vector_type(4))) unsigned short u16x4;
typedef __attribute__((ext_vector_type(8))) unsigned short u16x8;
typedef __attribute__((ext_vector_type(8))) short s16x8;

#define NH   32
#define NKV  8
#define HD   128
#define SEQ  2048
#define MTOK 4096   // BATCH*SEQ

__device__ __forceinline__ float b2f(unsigned short u) {
  union { float f; unsigned int i; } v; v.i = ((unsigned int)u) << 16; return v.f;
}
__device__ __forceinline__ unsigned short f2b(float f) {
  unsigned int i = __float_as_uint(f);
  return (unsigned short)((i + 0x7fffu + ((i >> 16) & 1u)) >> 16);
}

// ---------------- elementwise f32 -> bf16 ----------------
__global__ void convert_f32_bf16(const float* __restrict__ in,
                                 unsigned short* __restrict__ out, int n4) {
  int i = blockIdx.x * 256 + threadIdx.x;
  if (i >= n4) return;
  f32x4 v = *(const f32x4*)(in + (size_t)i * 4);
  u16x4 r;
  r.x = f2b(v.x); r.y = f2b(v.y); r.z = f2b(v.z); r.w = f2b(v.w);
  *(u16x4*)(out + (size_t)i * 4) = r;
}

// ---------------- transpose + convert: W (K=4096 x N) f32 -> WT (N x 4096) bf16 ----
__global__ void tconv(const float* __restrict__ W, unsigned short* __restrict__ WT, int N) {
  __shared__ float tile[32][33];
  int k0 = blockIdx.x * 32, n0 = blockIdx.y * 32;
  int t = threadIdx.x;
  int r = t >> 3;          // 0..31
  int c = (t & 7) * 4;     // 0..28
  f32x4 v = *(const f32x4*)&W[(size_t)(k0 + r) * N + n0 + c];
  tile[r][c + 0] = v.x; tile[r][c + 1] = v.y; tile[r][c + 2] = v.z; tile[r][c + 3] = v.w;
  __syncthreads();
  u16x4 o;
  o.x = f2b(tile[c + 0][r]); o.y = f2b(tile[c + 1][r]);
  o.z = f2b(tile[c + 2][r]); o.w = f2b(tile[c + 3][r]);
  *(u16x4*)&WT[(size_t)(n0 + r) * 4096 + k0 + c] = o;
}

// ---------------- V transpose: vb (b,s,kvh,d) -> vtb (b,kvh,d,s) bf16 -------------
__global__ void vtrans(const unsigned short* __restrict__ vb, unsigned short* __restrict__ vtb) {
  __shared__ unsigned short tile[32][36];
  int s0 = blockIdx.x * 32, d0 = blockIdx.y * 32;
  int bkv = blockIdx.z; int b = bkv >> 3, kvh = bkv & 7;
  int t = threadIdx.x;
  int r = t >> 3, c = (t & 7) * 4;
  u16x4 v = *(const u16x4*)&vb[((size_t)(b * SEQ + s0 + r) * NKV + kvh) * HD + d0 + c];
  tile[r][c + 0] = v.x; tile[r][c + 1] = v.y; tile[r][c + 2] = v.z; tile[r][c + 3] = v.w;
  __syncthreads();
  u16x4 o;
  o.x = tile[c + 0][r]; o.y = tile[c + 1][r]; o.z = tile[c + 2][r]; o.w = tile[c + 3][r];
  *(u16x4*)&vtb[((size_t)(b * NKV + kvh) * HD + d0 + r) * SEQ + s0 + c] = o;
}

// ---------------- RoPE in-place on bf16 (b,s,nh,128) -------------------------------
__global__ void rope_k(unsigned short* __restrict__ x, const float* __restrict__ cs,
                       const float* __restrict__ sn, int nhShift, int total) {
  int i = blockIdx.x * 256 + threadIdx.x;
  if (i >= total) return;
  int g = i & 15;                    // 16 groups of 8 elements within HD=128
  int rem = i >> 4;
  int h = rem & ((1 << nhShift) - 1);
  int sb = rem >> nhShift;           // b*SEQ + s
  int s = sb & (SEQ - 1);
  size_t base = (((size_t)sb << nhShift) + h) * HD + g * 8;
  u16x8 v = *(u16x8*)(x + base);
  f32x4 c = *(const f32x4*)(cs + s * 64 + g * 4);
  f32x4 sv = *(const f32x4*)(sn + s * 64 + g * 4);
#pragma unroll
  for (int j = 0; j < 4; ++j) {
    float re = b2f(v[2 * j]), im = b2f(v[2 * j + 1]);
    float cj = c[j], sj = sv[j];
    v[2 * j]     = f2b(re * cj - im * sj);
    v[2 * j + 1] = f2b(re * sj + im * cj);
  }
  *(u16x8*)(x + base) = v;
}

// ---------------- GEMM: C[M,N] = A[M,K](bf16) * BT[N,K](bf16)^T --------------------
// 128x128 tile, BK=64, 256 threads (4 waves, 2x2), 16x16x32 bf16 MFMA (m97 structure)
template <typename OutT>
__global__ __launch_bounds__(256, 2)
void gemm_bt(const unsigned short* __restrict__ A, const unsigned short* __restrict__ BT,
             OutT* __restrict__ C, int M, int N, int K) {
  __shared__ __align__(16) unsigned short As[128 * 64];
  __shared__ __align__(16) unsigned short Bs[128 * 64];
  const int t = threadIdx.x;
  const int lane = t & 63;
  const int w = t >> 6;
  const int l15 = lane & 15, l4 = lane >> 4;
  const int wm = w >> 1, wn = w & 1;
  const int m0 = blockIdx.x * 128, n0 = blockIdx.y * 128;

  f32x4 acc[4][4];
#pragma unroll
  for (int i = 0; i < 4; ++i)
#pragma unroll
    for (int j = 0; j < 4; ++j) acc[i][j] = (f32x4)(0.0f);

  for (int k0 = 0; k0 < K; k0 += 64) {
#pragma unroll
    for (int p = 0; p < 4; ++p) {
      int cb = p * 256 + w * 64;     // wave-uniform chunk base
      int c = cb + lane;
      int row = c >> 3, co = (c & 7) * 8;
      const unsigned short* srcA = A + (size_t)(m0 + row) * K + k0 + co;
      const unsigned short* srcB = BT + (size_t)(n0 + row) * K + k0 + co;
      __builtin_amdgcn_global_load_lds((const __attribute__((address_space(1))) void*)srcA,
                                       (__attribute__((address_space(3))) void*)(As + cb * 8),
                                       16, 0, 0);
      __builtin_amdgcn_global_load_lds((const __attribute__((address_space(1))) void*)srcB,
                                       (__attribute__((address_space(3))) void*)(Bs + cb * 8),
                                       16, 0, 0);
    }
    __syncthreads();
    s16x8 af[4][2], bfr[4][2];
#pragma unroll
    for (int mi = 0; mi < 4; ++mi)
#pragma unroll
      for (int kk = 0; kk < 2; ++kk)
        af[mi][kk] = *(const s16x8*)&As[(wm * 64 + mi * 16 + l15) * 64 + kk * 32 + l4 * 8];
#pragma unroll
    for (int ni = 0; ni < 4; ++ni)
#pragma unroll
      for (int kk = 0; kk < 2; ++kk)
        bfr[ni][kk] = *(const s16x8*)&Bs[(wn * 64 + ni * 16 + l15) * 64 + kk * 32 + l4 * 8];
#pragma unroll
    for (int kk = 0; kk < 2; ++kk)
#pragma unroll
      for (int mi = 0; mi < 4; ++mi)
#pragma unroll
        for (int ni = 0; ni < 4; ++ni)
          acc[mi][ni] = __builtin_amdgcn_mfma_f32_16x16x32_bf16(af[mi][kk], bfr[ni][kk],
                                                                acc[mi][ni], 0, 0, 0);
    __syncthreads();
  }
#pragma unroll
  for (int mi = 0; mi < 4; ++mi)
#pragma unroll
    for (int ni = 0; ni < 4; ++ni) {
      int col = n0 + wn * 64 + ni * 16 + l15;
#pragma unroll
      for (int r = 0; r < 4; ++r) {
        int row = m0 + wm * 64 + mi * 16 + l4 * 4 + r;
        if constexpr (sizeof(OutT) == 2)
          C[(size_t)row * N + col] = f2b(acc[mi][ni][r]);
        else
          C[(size_t)row * N + col] = acc[mi][ni][r];
      }
    }
}

// ---------------- Flash attention, causal, GQA 4:1 ---------------------------------
// v2: (1) longest-first block order (qt = 31 - bx>>6, slowest-varying) to kill the
//     drain tail behind the triangular work distribution (Occupancy was 16%);
// (2) async-STAGE split (T14): K/V for tile kt+1 loaded into regs during softmax+PV
//     of tile kt, LDS write after the post-PV barrier -> HBM/L2 latency hidden;
// (3) s_setprio(1) around MFMA clusters (T5).
__global__ __launch_bounds__(256, 2)
void attn_kernel(const unsigned short* __restrict__ qb, const unsigned short* __restrict__ kb,
                 const unsigned short* __restrict__ vtb, unsigned short* __restrict__ ab) {
  __shared__ __align__(16) unsigned short Ks[64 * 136];   // [key][d] pad +8
  __shared__ __align__(16) unsigned short Vs[128 * 72];   // [d][key] pad +8
  __shared__ __align__(16) unsigned short Ps[4 * 16 * 72];// per-wave [qrow][key] pad +8
  const int bx = (int)blockIdx.x;
  const int qt = 31 - (bx >> 6);     // heavy blocks (many KV tiles) first
  const int hb = bx & 63;
  const int h = hb >> 1;
  const int b = hb & 1;
  const int kvh = h >> 2;
  const int t = threadIdx.x, lane = t & 63, w = t >> 6;
  const int l15 = lane & 15, l4 = lane >> 4;
  const int q0 = qt * 64;
  const float SCALE = 0.08838834764831845f;  // 1/sqrt(128)

  // hoist Q fragments (A-operand: row = l15, k = kk*32 + l4*8 + j)
  size_t qoff = ((size_t)(b * SEQ + q0 + w * 16 + l15) * NH + h) * HD;
  s16x8 qf[4];
#pragma unroll
  for (int kk = 0; kk < 4; ++kk) qf[kk] = *(const s16x8*)(qb + qoff + kk * 32 + l4 * 8);

  f32x4 accO[8];
#pragma unroll
  for (int n = 0; n < 8; ++n) accO[n] = (f32x4)(0.0f);
  float mrow[4] = {-1e30f, -1e30f, -1e30f, -1e30f};
  float lrow[4] = {0.f, 0.f, 0.f, 0.f};
  unsigned short* Pw = Ps + w * 16 * 72;

  // staging registers for the async split (32 VGPRs)
  u16x8 kreg[4], vreg[4];
  auto load_tile = [&](int k0) {
#pragma unroll
    for (int p = 0; p < 4; ++p) {
      int c = p * 256 + t;
      int krow = c >> 4, kco = (c & 15) * 8;
      kreg[p] = *(const u16x8*)(kb + ((size_t)(b * SEQ + k0 + krow) * NKV + kvh) * HD + kco);
      int vrow = c >> 3, vco = (c & 7) * 8;
      vreg[p] = *(const u16x8*)(vtb + ((size_t)(b * NKV + kvh) * HD + vrow) * SEQ + k0 + vco);
    }
  };
  auto write_tile = [&]() {
#pragma unroll
    for (int p = 0; p < 4; ++p) {
      int c = p * 256 + t;
      *(u16x8*)&Ks[(c >> 4) * 136 + (c & 15) * 8] = kreg[p];
      *(u16x8*)&Vs[(c >> 3) * 72 + (c & 7) * 8] = vreg[p];
    }
  };

  load_tile(0);
  write_tile();
  __syncthreads();

  for (int kt = 0; kt <= qt; ++kt) {
    // S = Q K^T : 4 key-groups of 16, K-dim 128 = 4 MFMAs each
    f32x4 sc[4];
#pragma unroll
    for (int g = 0; g < 4; ++g) sc[g] = (f32x4)(0.0f);
    __builtin_amdgcn_s_setprio(1);
#pragma unroll
    for (int g = 0; g < 4; ++g)
#pragma unroll
      for (int kk = 0; kk < 4; ++kk) {
        s16x8 kf = *(const s16x8*)&Ks[(g * 16 + l15) * 136 + kk * 32 + l4 * 8];
        sc[g] = __builtin_amdgcn_mfma_f32_16x16x32_bf16(qf[kk], kf, sc[g], 0, 0, 0);
      }
    __builtin_amdgcn_s_setprio(0);

    // issue next tile's global loads now; latency hides under softmax + PV
    if (kt < qt) load_tile((kt + 1) * 64);

    // scale + causal mask (only diagonal tile needs mask)
    if (kt == qt) {
#pragma unroll
      for (int g = 0; g < 4; ++g)
#pragma unroll
        for (int r = 0; r < 4; ++r) {
          int key = g * 16 + l15;
          int qr = w * 16 + l4 * 4 + r;
          float v = sc[g][r] * SCALE;
          sc[g][r] = (key <= qr) ? v : -1e30f;
        }
    } else {
#pragma unroll
      for (int g = 0; g < 4; ++g)
#pragma unroll
        for (int r = 0; r < 4; ++r) sc[g][r] *= SCALE;
    }
    // online softmax: row stats via 16-lane butterfly (C row = l4*4+r)
    float resc[4], newm[4];
#pragma unroll
    for (int r = 0; r < 4; ++r) {
      float tm = fmaxf(fmaxf(sc[0][r], sc[1][r]), fmaxf(sc[2][r], sc[3][r]));
      tm = fmaxf(tm, __shfl_xor(tm, 1));
      tm = fmaxf(tm, __shfl_xor(tm, 2));
      tm = fmaxf(tm, __shfl_xor(tm, 4));
      tm = fmaxf(tm, __shfl_xor(tm, 8));
      newm[r] = fmaxf(mrow[r], tm);
      resc[r] = __expf(mrow[r] - newm[r]);
      mrow[r] = newm[r];
    }
    float pv[4][4];
#pragma unroll
    for (int g = 0; g < 4; ++g)
#pragma unroll
      for (int r = 0; r < 4; ++r) pv[g][r] = __expf(sc[g][r] - newm[r]);
#pragma unroll
    for (int r = 0; r < 4; ++r) {
      float s = pv[0][r] + pv[1][r] + pv[2][r] + pv[3][r];
      s += __shfl_xor(s, 1);
      s += __shfl_xor(s, 2);
      s += __shfl_xor(s, 4);
      s += __shfl_xor(s, 8);
      lrow[r] = lrow[r] * resc[r] + s;
    }
    // P -> wave-private LDS (bf16; same-wave reuse, no barrier needed), O rescale
#pragma unroll
    for (int g = 0; g < 4; ++g)
#pragma unroll
      for (int r = 0; r < 4; ++r) Pw[(l4 * 4 + r) * 72 + g * 16 + l15] = f2b(pv[g][r]);
#pragma unroll
    for (int n = 0; n < 8; ++n)
#pragma unroll
      for (int r = 0; r < 4; ++r) accO[n][r] *= resc[r];
    // O += P V : A = P (row=l15, k=key), B = V^T tile (col=l15 -> d)
    s16x8 pf[2];
    pf[0] = *(const s16x8*)&Pw[l15 * 72 + l4 * 8];
    pf[1] = *(const s16x8*)&Pw[l15 * 72 + 32 + l4 * 8];
    __builtin_amdgcn_s_setprio(1);
#pragma unroll
    for (int n = 0; n < 8; ++n)
#pragma unroll
      for (int kk = 0; kk < 2; ++kk) {
        s16x8 vf = *(const s16x8*)&Vs[(n * 16 + l15) * 72 + kk * 32 + l4 * 8];
        accO[n] = __builtin_amdgcn_mfma_f32_16x16x32_bf16(pf[kk], vf, accO[n], 0, 0, 0);
      }
    __builtin_amdgcn_s_setprio(0);

    __syncthreads();                 // all waves done reading Ks/Vs
    if (kt < qt) {
      write_tile();                  // regs -> LDS for tile kt+1
      __syncthreads();
    }
  }
  // epilogue: normalize and store bf16
  float inv[4];
#pragma unroll
  for (int r = 0; r < 4; ++r) inv[r] = 1.0f / lrow[r];
#pragma unroll
  for (int n = 0; n < 8; ++n)
#pragma unroll
    for (int r = 0; r < 4; ++r) {
      int s = q0 + w * 16 + l4 * 4 + r;
      ab[((size_t)(b * SEQ + s) * NH + h) * HD + n * 16 + l15] = f2b(accO[n][r] * inv[r]);
    }
}

// ---------------- launch -----------------------------------------------------------
extern "C" void kernel_launch(void* const* d_in, const int* in_sizes, int n_in,
                              void* d_out, int out_size, void* d_ws, size_t ws_size,
                              hipStream_t stream) {
  const float* x = (const float*)d_in[0];
  const float* wq = (const float*)d_in[1];
  const float* wk = (const float*)d_in[2];
  const float* wv = (const float*)d_in[3];
  const float* wo = (const float*)d_in[4];
  const float* fcos = (const float*)d_in[7];
  const float* fsin = (const float*)d_in[8];
  float* out = (float*)d_out;

  unsigned short* ws = (unsigned short*)d_ws;
  unsigned short* xb  = ws;                    // 16.78M el
  unsigned short* wqT = ws + 16777216;         // 16.78M
  unsigned short* wkT = ws + 33554432;         // 4.19M
  unsigned short* wvT = ws + 37748736;         // 4.19M
  unsigned short* woT = ws + 41943040;         // 16.78M
  unsigned short* qb  = ws + 58720256;         // 16.78M
  unsigned short* kb  = ws + 75497472;         // 4.19M
  unsigned short* vb  = ws + 79691776;         // 4.19M
  unsigned short* vtb = ws + 83886080;         // 4.19M
  unsigned short* ab  = ws + 88080384;         // 16.78M  (total ~200 MB)

  convert_f32_bf16<<<(4194304 + 255) / 256, 256, 0, stream>>>(x, xb, 4194304);
  tconv<<<dim3(128, 128), 256, 0, stream>>>(wq, wqT, 4096);
  tconv<<<dim3(128, 32), 256, 0, stream>>>(wk, wkT, 1024);
  tconv<<<dim3(128, 32), 256, 0, stream>>>(wv, wvT, 1024);
  tconv<<<dim3(128, 128), 256, 0, stream>>>(wo, woT, 4096);

  gemm_bt<unsigned short><<<dim3(32, 32), 256, 0, stream>>>(xb, wqT, qb, MTOK, 4096, 4096);
  gemm_bt<unsigned short><<<dim3(32, 8), 256, 0, stream>>>(xb, wkT, kb, MTOK, 1024, 4096);
  gemm_bt<unsigned short><<<dim3(32, 8), 256, 0, stream>>>(xb, wvT, vb, MTOK, 1024, 4096);

  rope_k<<<(2097152 + 255) / 256, 256, 0, stream>>>(qb, fcos, fsin, 5, 2097152);
  rope_k<<<(524288 + 255) / 256, 256, 0, stream>>>(kb, fcos, fsin, 3, 524288);

  vtrans<<<dim3(64, 4, 16), 256, 0, stream>>>(vb, vtb);

  attn_kernel<<<2048, 256, 0, stream>>>(qb, kb, vtb, ab);

  gemm_bt<float><<<dim3(32, 32), 256, 0, stream>>>(ab, woT, out, MTOK, 4096, 4096);
}

// Round 5
// 932.751 us; speedup vs baseline: 1.3544x; 1.1049x over previous
//
#include <hip/hip_runtime.h>
#include <stdint.h>

typedef __attribute__((ext_vector_type(4))) float f32x4;
typedef __attribute__((ext_vector_type(4))) unsigned short u16x4;
typedef __attribute__((ext_vector_type(8))) unsigned short u16x8;
typedef __attribute__((ext_vector_type(8))) short s16x8;

#define NH   32
#define NKV  8
#define HD   128
#define SEQ  2048
#define MTOK 4096   // BATCH*SEQ

__device__ __forceinline__ float b2f(unsigned short u) {
  union { float f; unsigned int i; } v; v.i = ((unsigned int)u) << 16; return v.f;
}
__device__ __forceinline__ unsigned short f2b(float f) {
  unsigned int i = __float_as_uint(f);
  return (unsigned short)((i + 0x7fffu + ((i >> 16) & 1u)) >> 16);
}

// ---------------- elementwise f32 -> bf16 ----------------
__global__ void convert_f32_bf16(const float* __restrict__ in,
                                 unsigned short* __restrict__ out, int n4) {
  int i = blockIdx.x * 256 + threadIdx.x;
  if (i >= n4) return;
  f32x4 v = *(const f32x4*)(in + (size_t)i * 4);
  u16x4 r;
  r.x = f2b(v.x); r.y = f2b(v.y); r.z = f2b(v.z); r.w = f2b(v.w);
  *(u16x4*)(out + (size_t)i * 4) = r;
}

// ---------------- transpose + convert: W (K=4096 x N) f32 -> WT (N x 4096) bf16 ----
__global__ void tconv(const float* __restrict__ W, unsigned short* __restrict__ WT, int N) {
  __shared__ float tile[32][33];
  int k0 = blockIdx.x * 32, n0 = blockIdx.y * 32;
  int t = threadIdx.x;
  int r = t >> 3;          // 0..31
  int c = (t & 7) * 4;     // 0..28
  f32x4 v = *(const f32x4*)&W[(size_t)(k0 + r) * N + n0 + c];
  tile[r][c + 0] = v.x; tile[r][c + 1] = v.y; tile[r][c + 2] = v.z; tile[r][c + 3] = v.w;
  __syncthreads();
  u16x4 o;
  o.x = f2b(tile[c + 0][r]); o.y = f2b(tile[c + 1][r]);
  o.z = f2b(tile[c + 2][r]); o.w = f2b(tile[c + 3][r]);
  *(u16x4*)&WT[(size_t)(n0 + r) * 4096 + k0 + c] = o;
}

// ---------------- V transpose: vb (b,s,kvh,d) -> vtb (b,kvh,d,s) bf16 -------------
__global__ void vtrans(const unsigned short* __restrict__ vb, unsigned short* __restrict__ vtb) {
  __shared__ unsigned short tile[32][36];
  int s0 = blockIdx.x * 32, d0 = blockIdx.y * 32;
  int bkv = blockIdx.z; int b = bkv >> 3, kvh = bkv & 7;
  int t = threadIdx.x;
  int r = t >> 3, c = (t & 7) * 4;
  u16x4 v = *(const u16x4*)&vb[((size_t)(b * SEQ + s0 + r) * NKV + kvh) * HD + d0 + c];
  tile[r][c + 0] = v.x; tile[r][c + 1] = v.y; tile[r][c + 2] = v.z; tile[r][c + 3] = v.w;
  __syncthreads();
  u16x4 o;
  o.x = tile[c + 0][r]; o.y = tile[c + 1][r]; o.z = tile[c + 2][r]; o.w = tile[c + 3][r];
  *(u16x4*)&vtb[((size_t)(b * NKV + kvh) * HD + d0 + r) * SEQ + s0 + c] = o;
}

// ---------------- RoPE in-place on bf16 (b,s,nh,128) -------------------------------
__global__ void rope_k(unsigned short* __restrict__ x, const float* __restrict__ cs,
                       const float* __restrict__ sn, int nhShift, int total) {
  int i = blockIdx.x * 256 + threadIdx.x;
  if (i >= total) return;
  int g = i & 15;                    // 16 groups of 8 elements within HD=128
  int rem = i >> 4;
  int h = rem & ((1 << nhShift) - 1);
  int sb = rem >> nhShift;           // b*SEQ + s
  int s = sb & (SEQ - 1);
  size_t base = (((size_t)sb << nhShift) + h) * HD + g * 8;
  u16x8 v = *(u16x8*)(x + base);
  f32x4 c = *(const f32x4*)(cs + s * 64 + g * 4);
  f32x4 sv = *(const f32x4*)(sn + s * 64 + g * 4);
#pragma unroll
  for (int j = 0; j < 4; ++j) {
    float re = b2f(v[2 * j]), im = b2f(v[2 * j + 1]);
    float cj = c[j], sj = sv[j];
    v[2 * j]     = f2b(re * cj - im * sj);
    v[2 * j + 1] = f2b(re * sj + im * cj);
  }
  *(u16x8*)(x + base) = v;
}

// ---------------- small GEMM (kept for N=1024 k/v proj): m97 128x128 structure -----
template <typename OutT>
__global__ __launch_bounds__(256, 2)
void gemm_bt(const unsigned short* __restrict__ A, const unsigned short* __restrict__ BT,
             OutT* __restrict__ C, int M, int N, int K) {
  __shared__ __align__(16) unsigned short As[128 * 64];
  __shared__ __align__(16) unsigned short Bs[128 * 64];
  const int t = threadIdx.x;
  const int lane = t & 63;
  const int w = t >> 6;
  const int l15 = lane & 15, l4 = lane >> 4;
  const int wm = w >> 1, wn = w & 1;
  const int m0 = blockIdx.x * 128, n0 = blockIdx.y * 128;

  f32x4 acc[4][4];
#pragma unroll
  for (int i = 0; i < 4; ++i)
#pragma unroll
    for (int j = 0; j < 4; ++j) acc[i][j] = (f32x4)(0.0f);

  for (int k0 = 0; k0 < K; k0 += 64) {
#pragma unroll
    for (int p = 0; p < 4; ++p) {
      int cb = p * 256 + w * 64;     // wave-uniform chunk base
      int c = cb + lane;
      int row = c >> 3, co = (c & 7) * 8;
      const unsigned short* srcA = A + (size_t)(m0 + row) * K + k0 + co;
      const unsigned short* srcB = BT + (size_t)(n0 + row) * K + k0 + co;
      __builtin_amdgcn_global_load_lds((const __attribute__((address_space(1))) void*)srcA,
                                       (__attribute__((address_space(3))) void*)(As + cb * 8),
                                       16, 0, 0);
      __builtin_amdgcn_global_load_lds((const __attribute__((address_space(1))) void*)srcB,
                                       (__attribute__((address_space(3))) void*)(Bs + cb * 8),
                                       16, 0, 0);
    }
    __syncthreads();
    s16x8 af[4][2], bfr[4][2];
#pragma unroll
    for (int mi = 0; mi < 4; ++mi)
#pragma unroll
      for (int kk = 0; kk < 2; ++kk)
        af[mi][kk] = *(const s16x8*)&As[(wm * 64 + mi * 16 + l15) * 64 + kk * 32 + l4 * 8];
#pragma unroll
    for (int ni = 0; ni < 4; ++ni)
#pragma unroll
      for (int kk = 0; kk < 2; ++kk)
        bfr[ni][kk] = *(const s16x8*)&Bs[(wn * 64 + ni * 16 + l15) * 64 + kk * 32 + l4 * 8];
#pragma unroll
    for (int kk = 0; kk < 2; ++kk)
#pragma unroll
      for (int mi = 0; mi < 4; ++mi)
#pragma unroll
        for (int ni = 0; ni < 4; ++ni)
          acc[mi][ni] = __builtin_amdgcn_mfma_f32_16x16x32_bf16(af[mi][kk], bfr[ni][kk],
                                                                acc[mi][ni], 0, 0, 0);
    __syncthreads();
  }
#pragma unroll
  for (int mi = 0; mi < 4; ++mi)
#pragma unroll
    for (int ni = 0; ni < 4; ++ni) {
      int col = n0 + wn * 64 + ni * 16 + l15;
#pragma unroll
      for (int r = 0; r < 4; ++r) {
        int row = m0 + wm * 64 + mi * 16 + l4 * 4 + r;
        if constexpr (sizeof(OutT) == 2)
          C[(size_t)row * N + col] = f2b(acc[mi][ni][r]);
        else
          C[(size_t)row * N + col] = acc[mi][ni][r];
      }
    }
}

// ---------------- big GEMM: 256x256 tile, 8 waves, counted-vmcnt pipeline ----------
// C[M,N] = A[M,K] * BT[N,K]^T, all bf16 in, OutT out.
// T3/T4: double-buffered LDS; next K-tile's 8 global_load_lds stay in flight across
//        compute (raw s_barrier + asm vmcnt(8), never drained to 0 mid-loop).
// T2:    16B-block XOR swizzle (blk ^= row&7) applied BOTH on the pre-swizzled global
//        source column (LDS dest stays linear for global_load_lds) and on ds_read.
// T5:    setprio(1) around MFMA clusters.
// Race audit: stage(buf^1) -> vmcnt(8) -> barrier -> compute(buf) -> barrier.
//  (a) stage at iter t writes buf[(t+1)&1], last read in iter t-1's compute, which is
//      sealed by the end-of-(t-1) barrier.
//  (b) compute reads of buf[t&1] follow every wave's own vmcnt(8) + barrier, so all
//      waves' loads for buf[t&1] have landed.
//  (c) reads complete before end barrier because MFMAs consume them (lgkm waits).
template <typename OutT>
__global__ __launch_bounds__(512, 2)
void gemm256(const unsigned short* __restrict__ A, const unsigned short* __restrict__ BT,
             OutT* __restrict__ C, int M, int N, int K) {
  __shared__ __align__(16) unsigned short As[2][256 * 64];
  __shared__ __align__(16) unsigned short Bs[2][256 * 64];
  const int t = threadIdx.x;
  const int lane = t & 63, w = t >> 6;
  const int l15 = lane & 15, l4 = lane >> 4;
  const int wr = w >> 2, wc = w & 3;          // 2 x 4 wave grid -> 128x64 per wave
  const int m0 = blockIdx.x * 256, n0 = blockIdx.y * 256;
  const int xk = l15 & 7;                     // ds_read swizzle key (row & 7)

  f32x4 acc[8][4];
#pragma unroll
  for (int i = 0; i < 8; ++i)
#pragma unroll
    for (int j = 0; j < 4; ++j) acc[i][j] = (f32x4)(0.0f);

  // stage one 256x64 K-tile of A and B into LDS buffer `buf` (8 global_load_lds).
  // thread covers elements e = p*4096 + t*8 (row r=e>>6, 16B-block bb=(e>>3)&7);
  // source column pre-swizzled so that swizzled ds_reads see logical data.
  auto stage = [&](int buf, int k0) {
#pragma unroll
    for (int p = 0; p < 4; ++p) {
      int e = p * 4096 + t * 8;
      int r = e >> 6;
      int bb = (e >> 3) & 7;
      int sc = (bb ^ (r & 7)) << 3;           // swizzled source column (elements)
      int cb = p * 4096 + w * 512;            // wave-uniform LDS element base
      __builtin_amdgcn_global_load_lds(
          (const __attribute__((address_space(1))) void*)(A + (size_t)(m0 + r) * K + k0 + sc),
          (__attribute__((address_space(3))) void*)(&As[buf][cb]), 16, 0, 0);
      __builtin_amdgcn_global_load_lds(
          (const __attribute__((address_space(1))) void*)(BT + (size_t)(n0 + r) * K + k0 + sc),
          (__attribute__((address_space(3))) void*)(&Bs[buf][cb]), 16, 0, 0);
    }
  };

  const int NT = K >> 6;
  stage(0, 0);
  asm volatile("s_waitcnt vmcnt(0)" ::: "memory");
  __builtin_amdgcn_s_barrier();
  __builtin_amdgcn_sched_barrier(0);

  for (int kt = 0; kt < NT; ++kt) {
    const int buf = kt & 1;
    if (kt + 1 < NT) {
      stage(buf ^ 1, (kt + 1) * 64);
      asm volatile("s_waitcnt vmcnt(8)" ::: "memory");   // buf's 8 loads done; next 8 in flight
    } else {
      asm volatile("s_waitcnt vmcnt(0)" ::: "memory");
    }
    __builtin_amdgcn_s_barrier();
    __builtin_amdgcn_sched_barrier(0);

#pragma unroll
    for (int kk = 0; kk < 2; ++kk) {
      s16x8 af[8], bfr[4];
#pragma unroll
      for (int mi = 0; mi < 8; ++mi) {
        int R = wr * 128 + mi * 16 + l15;
        af[mi] = *(const s16x8*)&As[buf][R * 64 + (((kk * 4 + l4) ^ xk) << 3)];
      }
#pragma unroll
      for (int ni = 0; ni < 4; ++ni) {
        int R = wc * 64 + ni * 16 + l15;
        bfr[ni] = *(const s16x8*)&Bs[buf][R * 64 + (((kk * 4 + l4) ^ xk) << 3)];
      }
      __builtin_amdgcn_s_setprio(1);
#pragma unroll
      for (int mi = 0; mi < 8; ++mi)
#pragma unroll
        for (int ni = 0; ni < 4; ++ni)
          acc[mi][ni] = __builtin_amdgcn_mfma_f32_16x16x32_bf16(af[mi], bfr[ni],
                                                                acc[mi][ni], 0, 0, 0);
      __builtin_amdgcn_s_setprio(0);
    }
    __builtin_amdgcn_s_barrier();
    __builtin_amdgcn_sched_barrier(0);
  }

#pragma unroll
  for (int mi = 0; mi < 8; ++mi)
#pragma unroll
    for (int ni = 0; ni < 4; ++ni) {
      int col = n0 + wc * 64 + ni * 16 + l15;
      int rowb = m0 + wr * 128 + mi * 16 + l4 * 4;
#pragma unroll
      for (int r = 0; r < 4; ++r) {
        if constexpr (sizeof(OutT) == 2)
          C[(size_t)(rowb + r) * N + col] = f2b(acc[mi][ni][r]);
        else
          C[(size_t)(rowb + r) * N + col] = acc[mi][ni][r];
      }
    }
}

// ---------------- Flash attention, causal, GQA 4:1 ---------------------------------
// longest-first block order; async-STAGE split (T14); setprio (T5).
__global__ __launch_bounds__(256, 2)
void attn_kernel(const unsigned short* __restrict__ qb, const unsigned short* __restrict__ kb,
                 const unsigned short* __restrict__ vtb, unsigned short* __restrict__ ab) {
  __shared__ __align__(16) unsigned short Ks[64 * 136];   // [key][d] pad +8
  __shared__ __align__(16) unsigned short Vs[128 * 72];   // [d][key] pad +8
  __shared__ __align__(16) unsigned short Ps[4 * 16 * 72];// per-wave [qrow][key] pad +8
  const int bx = (int)blockIdx.x;
  const int qt = 31 - (bx >> 6);     // heavy blocks (many KV tiles) first
  const int hb = bx & 63;
  const int h = hb >> 1;
  const int b = hb & 1;
  const int kvh = h >> 2;
  const int t = threadIdx.x, lane = t & 63, w = t >> 6;
  const int l15 = lane & 15, l4 = lane >> 4;
  const int q0 = qt * 64;
  const float SCALE = 0.08838834764831845f;  // 1/sqrt(128)

  size_t qoff = ((size_t)(b * SEQ + q0 + w * 16 + l15) * NH + h) * HD;
  s16x8 qf[4];
#pragma unroll
  for (int kk = 0; kk < 4; ++kk) qf[kk] = *(const s16x8*)(qb + qoff + kk * 32 + l4 * 8);

  f32x4 accO[8];
#pragma unroll
  for (int n = 0; n < 8; ++n) accO[n] = (f32x4)(0.0f);
  float mrow[4] = {-1e30f, -1e30f, -1e30f, -1e30f};
  float lrow[4] = {0.f, 0.f, 0.f, 0.f};
  unsigned short* Pw = Ps + w * 16 * 72;

  u16x8 kreg[4], vreg[4];
  auto load_tile = [&](int k0) {
#pragma unroll
    for (int p = 0; p < 4; ++p) {
      int c = p * 256 + t;
      int krow = c >> 4, kco = (c & 15) * 8;
      kreg[p] = *(const u16x8*)(kb + ((size_t)(b * SEQ + k0 + krow) * NKV + kvh) * HD + kco);
      int vrow = c >> 3, vco = (c & 7) * 8;
      vreg[p] = *(const u16x8*)(vtb + ((size_t)(b * NKV + kvh) * HD + vrow) * SEQ + k0 + vco);
    }
  };
  auto write_tile = [&]() {
#pragma unroll
    for (int p = 0; p < 4; ++p) {
      int c = p * 256 + t;
      *(u16x8*)&Ks[(c >> 4) * 136 + (c & 15) * 8] = kreg[p];
      *(u16x8*)&Vs[(c >> 3) * 72 + (c & 7) * 8] = vreg[p];
    }
  };

  load_tile(0);
  write_tile();
  __syncthreads();

  for (int kt = 0; kt <= qt; ++kt) {
    f32x4 sc[4];
#pragma unroll
    for (int g = 0; g < 4; ++g) sc[g] = (f32x4)(0.0f);
    __builtin_amdgcn_s_setprio(1);
#pragma unroll
    for (int g = 0; g < 4; ++g)
#pragma unroll
      for (int kk = 0; kk < 4; ++kk) {
        s16x8 kf = *(const s16x8*)&Ks[(g * 16 + l15) * 136 + kk * 32 + l4 * 8];
        sc[g] = __builtin_amdgcn_mfma_f32_16x16x32_bf16(qf[kk], kf, sc[g], 0, 0, 0);
      }
    __builtin_amdgcn_s_setprio(0);

    if (kt < qt) load_tile((kt + 1) * 64);

    if (kt == qt) {
#pragma unroll
      for (int g = 0; g < 4; ++g)
#pragma unroll
        for (int r = 0; r < 4; ++r) {
          int key = g * 16 + l15;
          int qr = w * 16 + l4 * 4 + r;
          float v = sc[g][r] * SCALE;
          sc[g][r] = (key <= qr) ? v : -1e30f;
        }
    } else {
#pragma unroll
      for (int g = 0; g < 4; ++g)
#pragma unroll
        for (int r = 0; r < 4; ++r) sc[g][r] *= SCALE;
    }
    float resc[4], newm[4];
#pragma unroll
    for (int r = 0; r < 4; ++r) {
      float tm = fmaxf(fmaxf(sc[0][r], sc[1][r]), fmaxf(sc[2][r], sc[3][r]));
      tm = fmaxf(tm, __shfl_xor(tm, 1));
      tm = fmaxf(tm, __shfl_xor(tm, 2));
      tm = fmaxf(tm, __shfl_xor(tm, 4));
      tm = fmaxf(tm, __shfl_xor(tm, 8));
      newm[r] = fmaxf(mrow[r], tm);
      resc[r] = __expf(mrow[r] - newm[r]);
      mrow[r] = newm[r];
    }
    float pv[4][4];
#pragma unroll
    for (int g = 0; g < 4; ++g)
#pragma unroll
      for (int r = 0; r < 4; ++r) pv[g][r] = __expf(sc[g][r] - newm[r]);
#pragma unroll
    for (int r = 0; r < 4; ++r) {
      float s = pv[0][r] + pv[1][r] + pv[2][r] + pv[3][r];
      s += __shfl_xor(s, 1);
      s += __shfl_xor(s, 2);
      s += __shfl_xor(s, 4);
      s += __shfl_xor(s, 8);
      lrow[r] = lrow[r] * resc[r] + s;
    }
#pragma unroll
    for (int g = 0; g < 4; ++g)
#pragma unroll
      for (int r = 0; r < 4; ++r) Pw[(l4 * 4 + r) * 72 + g * 16 + l15] = f2b(pv[g][r]);
#pragma unroll
    for (int n = 0; n < 8; ++n)
#pragma unroll
      for (int r = 0; r < 4; ++r) accO[n][r] *= resc[r];
    s16x8 pf[2];
    pf[0] = *(const s16x8*)&Pw[l15 * 72 + l4 * 8];
    pf[1] = *(const s16x8*)&Pw[l15 * 72 + 32 + l4 * 8];
    __builtin_amdgcn_s_setprio(1);
#pragma unroll
    for (int n = 0; n < 8; ++n)
#pragma unroll
      for (int kk = 0; kk < 2; ++kk) {
        s16x8 vf = *(const s16x8*)&Vs[(n * 16 + l15) * 72 + kk * 32 + l4 * 8];
        accO[n] = __builtin_amdgcn_mfma_f32_16x16x32_bf16(pf[kk], vf, accO[n], 0, 0, 0);
      }
    __builtin_amdgcn_s_setprio(0);

    __syncthreads();
    if (kt < qt) {
      write_tile();
      __syncthreads();
    }
  }
  float inv[4];
#pragma unroll
  for (int r = 0; r < 4; ++r) inv[r] = 1.0f / lrow[r];
#pragma unroll
  for (int n = 0; n < 8; ++n)
#pragma unroll
    for (int r = 0; r < 4; ++r) {
      int s = q0 + w * 16 + l4 * 4 + r;
      ab[((size_t)(b * SEQ + s) * NH + h) * HD + n * 16 + l15] = f2b(accO[n][r] * inv[r]);
    }
}

// ---------------- launch -----------------------------------------------------------
extern "C" void kernel_launch(void* const* d_in, const int* in_sizes, int n_in,
                              void* d_out, int out_size, void* d_ws, size_t ws_size,
                              hipStream_t stream) {
  const float* x = (const float*)d_in[0];
  const float* wq = (const float*)d_in[1];
  const float* wk = (const float*)d_in[2];
  const float* wv = (const float*)d_in[3];
  const float* wo = (const float*)d_in[4];
  const float* fcos = (const float*)d_in[7];
  const float* fsin = (const float*)d_in[8];
  float* out = (float*)d_out;

  unsigned short* ws = (unsigned short*)d_ws;
  unsigned short* xb  = ws;                    // 16.78M el
  unsigned short* wqT = ws + 16777216;         // 16.78M
  unsigned short* wkT = ws + 33554432;         // 4.19M
  unsigned short* wvT = ws + 37748736;         // 4.19M
  unsigned short* woT = ws + 41943040;         // 16.78M
  unsigned short* qb  = ws + 58720256;         // 16.78M
  unsigned short* kb  = ws + 75497472;         // 4.19M
  unsigned short* vb  = ws + 79691776;         // 4.19M
  unsigned short* vtb = ws + 83886080;         // 4.19M
  unsigned short* ab  = ws + 88080384;         // 16.78M  (total ~200 MB)

  convert_f32_bf16<<<(4194304 + 255) / 256, 256, 0, stream>>>(x, xb, 4194304);
  tconv<<<dim3(128, 128), 256, 0, stream>>>(wq, wqT, 4096);
  tconv<<<dim3(128, 32), 256, 0, stream>>>(wk, wkT, 1024);
  tconv<<<dim3(128, 32), 256, 0, stream>>>(wv, wvT, 1024);
  tconv<<<dim3(128, 128), 256, 0, stream>>>(wo, woT, 4096);

  gemm256<unsigned short><<<dim3(16, 16), 512, 0, stream>>>(xb, wqT, qb, MTOK, 4096, 4096);
  gemm_bt<unsigned short><<<dim3(32, 8), 256, 0, stream>>>(xb, wkT, kb, MTOK, 1024, 4096);
  gemm_bt<unsigned short><<<dim3(32, 8), 256, 0, stream>>>(xb, wvT, vb, MTOK, 1024, 4096);

  rope_k<<<(2097152 + 255) / 256, 256, 0, stream>>>(qb, fcos, fsin, 5, 2097152);
  rope_k<<<(524288 + 255) / 256, 256, 0, stream>>>(kb, fcos, fsin, 3, 524288);

  vtrans<<<dim3(64, 4, 16), 256, 0, stream>>>(vb, vtb);

  attn_kernel<<<2048, 256, 0, stream>>>(qb, kb, vtb, ab);

  gemm256<float><<<dim3(16, 16), 512, 0, stream>>>(ab, woT, out, MTOK, 4096, 4096);
}

// Round 6
// 903.922 us; speedup vs baseline: 1.3976x; 1.0319x over previous
//
#include <hip/hip_runtime.h>
#include <stdint.h>

typedef __attribute__((ext_vector_type(4))) float f32x4;
typedef __attribute__((ext_vector_type(4))) unsigned short u16x4;
typedef __attribute__((ext_vector_type(8))) unsigned short u16x8;
typedef __attribute__((ext_vector_type(8))) short s16x8;

#define NH   32
#define NKV  8
#define HD   128
#define SEQ  2048
#define MTOK 4096   // BATCH*SEQ

__device__ __forceinline__ float b2f(unsigned short u) {
  union { float f; unsigned int i; } v; v.i = ((unsigned int)u) << 16; return v.f;
}
__device__ __forceinline__ unsigned short f2b(float f) {
  unsigned int i = __float_as_uint(f);
  return (unsigned short)((i + 0x7fffu + ((i >> 16) & 1u)) >> 16);
}

// ---------------- elementwise f32 -> bf16 ----------------
__global__ void convert_f32_bf16(const float* __restrict__ in,
                                 unsigned short* __restrict__ out, int n4) {
  int i = blockIdx.x * 256 + threadIdx.x;
  if (i >= n4) return;
  f32x4 v = *(const f32x4*)(in + (size_t)i * 4);
  u16x4 r;
  r.x = f2b(v.x); r.y = f2b(v.y); r.z = f2b(v.z); r.w = f2b(v.w);
  *(u16x4*)(out + (size_t)i * 4) = r;
}

// ---------------- transpose + convert: W (K=4096 x N) f32 -> WT (N x 4096) bf16 ----
__global__ void tconv(const float* __restrict__ W, unsigned short* __restrict__ WT, int N) {
  __shared__ float tile[32][33];
  int k0 = blockIdx.x * 32, n0 = blockIdx.y * 32;
  int t = threadIdx.x;
  int r = t >> 3;          // 0..31
  int c = (t & 7) * 4;     // 0..28
  f32x4 v = *(const f32x4*)&W[(size_t)(k0 + r) * N + n0 + c];
  tile[r][c + 0] = v.x; tile[r][c + 1] = v.y; tile[r][c + 2] = v.z; tile[r][c + 3] = v.w;
  __syncthreads();
  u16x4 o;
  o.x = f2b(tile[c + 0][r]); o.y = f2b(tile[c + 1][r]);
  o.z = f2b(tile[c + 2][r]); o.w = f2b(tile[c + 3][r]);
  *(u16x4*)&WT[(size_t)(n0 + r) * 4096 + k0 + c] = o;
}

// ---------------- V transpose: kvb v-part (b,s,kvh,d) -> vtb (b,kvh,d,s) bf16 ------
__global__ void vtrans(const unsigned short* __restrict__ kvb, unsigned short* __restrict__ vtb) {
  __shared__ unsigned short tile[32][36];
  int s0 = blockIdx.x * 32, d0 = blockIdx.y * 32;
  int bkv = blockIdx.z; int b = bkv >> 3, kvh = bkv & 7;
  int t = threadIdx.x;
  int r = t >> 3, c = (t & 7) * 4;
  u16x4 v = *(const u16x4*)&kvb[(size_t)(b * SEQ + s0 + r) * 2048 + 1024 + kvh * HD + d0 + c];
  tile[r][c + 0] = v.x; tile[r][c + 1] = v.y; tile[r][c + 2] = v.z; tile[r][c + 3] = v.w;
  __syncthreads();
  u16x4 o;
  o.x = tile[c + 0][r]; o.y = tile[c + 1][r]; o.z = tile[c + 2][r]; o.w = tile[c + 3][r];
  *(u16x4*)&vtb[((size_t)(b * NKV + kvh) * HD + d0 + r) * SEQ + s0 + c] = o;
}

// ---------------- RoPE in-place on bf16 q (b,s,nh,128) -----------------------------
__global__ void rope_k(unsigned short* __restrict__ x, const float* __restrict__ cs,
                       const float* __restrict__ sn, int nhShift, int total) {
  int i = blockIdx.x * 256 + threadIdx.x;
  if (i >= total) return;
  int g = i & 15;                    // 16 groups of 8 elements within HD=128
  int rem = i >> 4;
  int h = rem & ((1 << nhShift) - 1);
  int sb = rem >> nhShift;           // b*SEQ + s
  int s = sb & (SEQ - 1);
  size_t base = (((size_t)sb << nhShift) + h) * HD + g * 8;
  u16x8 v = *(u16x8*)(x + base);
  f32x4 c = *(const f32x4*)(cs + s * 64 + g * 4);
  f32x4 sv = *(const f32x4*)(sn + s * 64 + g * 4);
#pragma unroll
  for (int j = 0; j < 4; ++j) {
    float re = b2f(v[2 * j]), im = b2f(v[2 * j + 1]);
    float cj = c[j], sj = sv[j];
    v[2 * j]     = f2b(re * cj - im * sj);
    v[2 * j + 1] = f2b(re * sj + im * cj);
  }
  *(u16x8*)(x + base) = v;
}

// ---------------- RoPE on k-part of kvb (token row stride 2048) ---------------------
__global__ void rope_kv(unsigned short* __restrict__ kvb, const float* __restrict__ cs,
                        const float* __restrict__ sn, int total) {
  int i = blockIdx.x * 256 + threadIdx.x;
  if (i >= total) return;
  int g = i & 15;
  int rem = i >> 4;
  int h = rem & 7;                   // kv head
  int sb = rem >> 3;                 // b*SEQ + s
  int s = sb & (SEQ - 1);
  size_t base = (size_t)sb * 2048 + h * HD + g * 8;
  u16x8 v = *(u16x8*)(kvb + base);
  f32x4 c = *(const f32x4*)(cs + s * 64 + g * 4);
  f32x4 sv = *(const f32x4*)(sn + s * 64 + g * 4);
#pragma unroll
  for (int j = 0; j < 4; ++j) {
    float re = b2f(v[2 * j]), im = b2f(v[2 * j + 1]);
    float cj = c[j], sj = sv[j];
    v[2 * j]     = f2b(re * cj - im * sj);
    v[2 * j + 1] = f2b(re * sj + im * cj);
  }
  *(u16x8*)(kvb + base) = v;
}

// ---------------- small GEMM (kv proj, N=2048): m97 128x128 structure --------------
template <typename OutT>
__global__ __launch_bounds__(256, 2)
void gemm_bt(const unsigned short* __restrict__ A, const unsigned short* __restrict__ BT,
             OutT* __restrict__ C, int M, int N, int K) {
  __shared__ __align__(16) unsigned short As[128 * 64];
  __shared__ __align__(16) unsigned short Bs[128 * 64];
  const int t = threadIdx.x;
  const int lane = t & 63;
  const int w = t >> 6;
  const int l15 = lane & 15, l4 = lane >> 4;
  const int wm = w >> 1, wn = w & 1;
  const int m0 = blockIdx.x * 128, n0 = blockIdx.y * 128;

  f32x4 acc[4][4];
#pragma unroll
  for (int i = 0; i < 4; ++i)
#pragma unroll
    for (int j = 0; j < 4; ++j) acc[i][j] = (f32x4)(0.0f);

  for (int k0 = 0; k0 < K; k0 += 64) {
#pragma unroll
    for (int p = 0; p < 4; ++p) {
      int cb = p * 256 + w * 64;     // wave-uniform chunk base
      int c = cb + lane;
      int row = c >> 3, co = (c & 7) * 8;
      const unsigned short* srcA = A + (size_t)(m0 + row) * K + k0 + co;
      const unsigned short* srcB = BT + (size_t)(n0 + row) * K + k0 + co;
      __builtin_amdgcn_global_load_lds((const __attribute__((address_space(1))) void*)srcA,
                                       (__attribute__((address_space(3))) void*)(As + cb * 8),
                                       16, 0, 0);
      __builtin_amdgcn_global_load_lds((const __attribute__((address_space(1))) void*)srcB,
                                       (__attribute__((address_space(3))) void*)(Bs + cb * 8),
                                       16, 0, 0);
    }
    __syncthreads();
    s16x8 af[4][2], bfr[4][2];
#pragma unroll
    for (int mi = 0; mi < 4; ++mi)
#pragma unroll
      for (int kk = 0; kk < 2; ++kk)
        af[mi][kk] = *(const s16x8*)&As[(wm * 64 + mi * 16 + l15) * 64 + kk * 32 + l4 * 8];
#pragma unroll
    for (int ni = 0; ni < 4; ++ni)
#pragma unroll
      for (int kk = 0; kk < 2; ++kk)
        bfr[ni][kk] = *(const s16x8*)&Bs[(wn * 64 + ni * 16 + l15) * 64 + kk * 32 + l4 * 8];
#pragma unroll
    for (int kk = 0; kk < 2; ++kk)
#pragma unroll
      for (int mi = 0; mi < 4; ++mi)
#pragma unroll
        for (int ni = 0; ni < 4; ++ni)
          acc[mi][ni] = __builtin_amdgcn_mfma_f32_16x16x32_bf16(af[mi][kk], bfr[ni][kk],
                                                                acc[mi][ni], 0, 0, 0);
    __syncthreads();
  }
#pragma unroll
  for (int mi = 0; mi < 4; ++mi)
#pragma unroll
    for (int ni = 0; ni < 4; ++ni) {
      int col = n0 + wn * 64 + ni * 16 + l15;
#pragma unroll
      for (int r = 0; r < 4; ++r) {
        int row = m0 + wm * 64 + mi * 16 + l4 * 4 + r;
        if constexpr (sizeof(OutT) == 2)
          C[(size_t)row * N + col] = f2b(acc[mi][ni][r]);
        else
          C[(size_t)row * N + col] = acc[mi][ni][r];
      }
    }
}

// ---------------- big GEMM: 256x256 tile, 8 waves, counted vmcnt + 2-phase split ---
// r6: adds T3 phase-split (2 {ds_read; lgkm; MFMA; barrier} phases per K-tile) and
// bijective XCD swizzle (nwg=256 = 8 XCD x 32). Counted vmcnt(8) keeps next tile's
// loads in flight across the whole compute (T4). T2 both-sides 16B-block XOR swizzle.
// Race audit: all ds_reads of buf occur after every wave's own vmcnt(8) + s_barrier
// (all loads for buf landed); stage targets buf^1 (disjoint LDS).
template <typename OutT>
__global__ __launch_bounds__(512, 2)
void gemm256(const unsigned short* __restrict__ A, const unsigned short* __restrict__ BT,
             OutT* __restrict__ C, int M, int N, int K) {
  __shared__ __align__(16) unsigned short As[2][256 * 64];
  __shared__ __align__(16) unsigned short Bs[2][256 * 64];
  const int t = threadIdx.x;
  const int lane = t & 63, w = t >> 6;
  const int l15 = lane & 15, l4 = lane >> 4;
  const int wr = w >> 2, wc = w & 3;          // 2 x 4 wave grid -> 128x64 per wave
  // XCD-aware remap: 256 wgs = 8 XCDs x 32; each XCD covers 2 n-panels x 16 m-panels
  const int flat = (int)blockIdx.x + 16 * (int)blockIdx.y;
  const int f2 = (flat & 7) * 32 + (flat >> 3);
  const int m0 = (f2 & 15) * 256, n0 = (f2 >> 4) * 256;
  const int xk = l15 & 7;                     // ds_read swizzle key (row & 7)

  f32x4 acc[8][4];
#pragma unroll
  for (int i = 0; i < 8; ++i)
#pragma unroll
    for (int j = 0; j < 4; ++j) acc[i][j] = (f32x4)(0.0f);

  auto stage = [&](int buf, int k0) {
#pragma unroll
    for (int p = 0; p < 4; ++p) {
      int e = p * 4096 + t * 8;
      int r = e >> 6;
      int bb = (e >> 3) & 7;
      int sc = (bb ^ (r & 7)) << 3;           // swizzled source column (elements)
      int cb = p * 4096 + w * 512;            // wave-uniform LDS element base
      __builtin_amdgcn_global_load_lds(
          (const __attribute__((address_space(1))) void*)(A + (size_t)(m0 + r) * K + k0 + sc),
          (__attribute__((address_space(3))) void*)(&As[buf][cb]), 16, 0, 0);
      __builtin_amdgcn_global_load_lds(
          (const __attribute__((address_space(1))) void*)(BT + (size_t)(n0 + r) * K + k0 + sc),
          (__attribute__((address_space(3))) void*)(&Bs[buf][cb]), 16, 0, 0);
    }
  };

  const int NT = K >> 6;
  stage(0, 0);
  asm volatile("s_waitcnt vmcnt(0)" ::: "memory");
  __builtin_amdgcn_s_barrier();
  __builtin_amdgcn_sched_barrier(0);

  for (int kt = 0; kt < NT; ++kt) {
    const int buf = kt & 1;
    if (kt + 1 < NT) {
      stage(buf ^ 1, (kt + 1) * 64);
      asm volatile("s_waitcnt vmcnt(8)" ::: "memory");   // buf's 8 landed; 8 in flight
    } else {
      asm volatile("s_waitcnt vmcnt(0)" ::: "memory");
    }
    __builtin_amdgcn_s_barrier();
    __builtin_amdgcn_sched_barrier(0);

#pragma unroll
    for (int kk = 0; kk < 2; ++kk) {
      s16x8 af[8], bfr[4];
#pragma unroll
      for (int mi = 0; mi < 8; ++mi) {
        int R = wr * 128 + mi * 16 + l15;
        af[mi] = *(const s16x8*)&As[buf][R * 64 + (((kk * 4 + l4) ^ xk) << 3)];
      }
#pragma unroll
      for (int ni = 0; ni < 4; ++ni) {
        int R = wc * 64 + ni * 16 + l15;
        bfr[ni] = *(const s16x8*)&Bs[buf][R * 64 + (((kk * 4 + l4) ^ xk) << 3)];
      }
      asm volatile("s_waitcnt lgkmcnt(0)" ::: "memory");
      __builtin_amdgcn_sched_barrier(0);
      __builtin_amdgcn_s_setprio(1);
#pragma unroll
      for (int mi = 0; mi < 8; ++mi)
#pragma unroll
        for (int ni = 0; ni < 4; ++ni)
          acc[mi][ni] = __builtin_amdgcn_mfma_f32_16x16x32_bf16(af[mi], bfr[ni],
                                                                acc[mi][ni], 0, 0, 0);
      __builtin_amdgcn_s_setprio(0);
      __builtin_amdgcn_s_barrier();
      __builtin_amdgcn_sched_barrier(0);
    }
  }

#pragma unroll
  for (int mi = 0; mi < 8; ++mi)
#pragma unroll
    for (int ni = 0; ni < 4; ++ni) {
      int col = n0 + wc * 64 + ni * 16 + l15;
      int rowb = m0 + wr * 128 + mi * 16 + l4 * 4;
#pragma unroll
      for (int r = 0; r < 4; ++r) {
        if constexpr (sizeof(OutT) == 2)
          C[(size_t)(rowb + r) * N + col] = f2b(acc[mi][ni][r]);
        else
          C[(size_t)(rowb + r) * N + col] = acc[mi][ni][r];
      }
    }
}

// ---------------- Flash attention, causal, GQA 4:1 ---------------------------------
// longest-first block order; async-STAGE split (T14); setprio (T5); defer-max (T13).
__global__ __launch_bounds__(256, 2)
void attn_kernel(const unsigned short* __restrict__ qb, const unsigned short* __restrict__ kvb,
                 const unsigned short* __restrict__ vtb, unsigned short* __restrict__ ab) {
  __shared__ __align__(16) unsigned short Ks[64 * 136];   // [key][d] pad +8
  __shared__ __align__(16) unsigned short Vs[128 * 72];   // [d][key] pad +8
  __shared__ __align__(16) unsigned short Ps[4 * 16 * 72];// per-wave [qrow][key] pad +8
  const int bx = (int)blockIdx.x;
  const int qt = 31 - (bx >> 6);     // heavy blocks (many KV tiles) first
  const int hb = bx & 63;
  const int h = hb >> 1;
  const int b = hb & 1;
  const int kvh = h >> 2;
  const int t = threadIdx.x, lane = t & 63, w = t >> 6;
  const int l15 = lane & 15, l4 = lane >> 4;
  const int q0 = qt * 64;
  const float SCALE = 0.08838834764831845f;  // 1/sqrt(128)

  size_t qoff = ((size_t)(b * SEQ + q0 + w * 16 + l15) * NH + h) * HD;
  s16x8 qf[4];
#pragma unroll
  for (int kk = 0; kk < 4; ++kk) qf[kk] = *(const s16x8*)(qb + qoff + kk * 32 + l4 * 8);

  f32x4 accO[8];
#pragma unroll
  for (int n = 0; n < 8; ++n) accO[n] = (f32x4)(0.0f);
  float mrow[4] = {-1e30f, -1e30f, -1e30f, -1e30f};
  float lrow[4] = {0.f, 0.f, 0.f, 0.f};
  unsigned short* Pw = Ps + w * 16 * 72;

  u16x8 kreg[4], vreg[4];
  auto load_tile = [&](int k0) {
#pragma unroll
    for (int p = 0; p < 4; ++p) {
      int c = p * 256 + t;
      int krow = c >> 4, kco = (c & 15) * 8;
      kreg[p] = *(const u16x8*)(kvb + (size_t)(b * SEQ + k0 + krow) * 2048 + kvh * HD + kco);
      int vrow = c >> 3, vco = (c & 7) * 8;
      vreg[p] = *(const u16x8*)(vtb + ((size_t)(b * NKV + kvh) * HD + vrow) * SEQ + k0 + vco);
    }
  };
  auto write_tile = [&]() {
#pragma unroll
    for (int p = 0; p < 4; ++p) {
      int c = p * 256 + t;
      *(u16x8*)&Ks[(c >> 4) * 136 + (c & 15) * 8] = kreg[p];
      *(u16x8*)&Vs[(c >> 3) * 72 + (c & 7) * 8] = vreg[p];
    }
  };

  load_tile(0);
  write_tile();
  __syncthreads();

  for (int kt = 0; kt <= qt; ++kt) {
    f32x4 sc[4];
#pragma unroll
    for (int g = 0; g < 4; ++g) sc[g] = (f32x4)(0.0f);
    __builtin_amdgcn_s_setprio(1);
#pragma unroll
    for (int g = 0; g < 4; ++g)
#pragma unroll
      for (int kk = 0; kk < 4; ++kk) {
        s16x8 kf = *(const s16x8*)&Ks[(g * 16 + l15) * 136 + kk * 32 + l4 * 8];
        sc[g] = __builtin_amdgcn_mfma_f32_16x16x32_bf16(qf[kk], kf, sc[g], 0, 0, 0);
      }
    __builtin_amdgcn_s_setprio(0);

    if (kt < qt) load_tile((kt + 1) * 64);

    if (kt == qt) {
#pragma unroll
      for (int g = 0; g < 4; ++g)
#pragma unroll
        for (int r = 0; r < 4; ++r) {
          int key = g * 16 + l15;
          int qr = w * 16 + l4 * 4 + r;
          float v = sc[g][r] * SCALE;
          sc[g][r] = (key <= qr) ? v : -1e30f;
        }
    } else {
#pragma unroll
      for (int g = 0; g < 4; ++g)
#pragma unroll
        for (int r = 0; r < 4; ++r) sc[g][r] *= SCALE;
    }
    // tile max per row
    float tm[4];
#pragma unroll
    for (int r = 0; r < 4; ++r) {
      float v = fmaxf(fmaxf(sc[0][r], sc[1][r]), fmaxf(sc[2][r], sc[3][r]));
      v = fmaxf(v, __shfl_xor(v, 1));
      v = fmaxf(v, __shfl_xor(v, 2));
      v = fmaxf(v, __shfl_xor(v, 4));
      v = fmaxf(v, __shfl_xor(v, 8));
      tm[r] = v;
    }
    // defer-max (T13): only rescale when some row's max grew by > 8
    bool grow = (tm[0] > mrow[0] + 8.f) || (tm[1] > mrow[1] + 8.f) ||
                (tm[2] > mrow[2] + 8.f) || (tm[3] > mrow[3] + 8.f);
    if (__any(grow)) {
#pragma unroll
      for (int r = 0; r < 4; ++r) {
        float nm = fmaxf(mrow[r], tm[r]);
        float rs = __expf(mrow[r] - nm);
        mrow[r] = nm;
        lrow[r] *= rs;
#pragma unroll
        for (int n = 0; n < 8; ++n) accO[n][r] *= rs;
      }
    }
    float pv[4][4];
#pragma unroll
    for (int g = 0; g < 4; ++g)
#pragma unroll
      for (int r = 0; r < 4; ++r) pv[g][r] = __expf(sc[g][r] - mrow[r]);
#pragma unroll
    for (int r = 0; r < 4; ++r) {
      float s = pv[0][r] + pv[1][r] + pv[2][r] + pv[3][r];
      s += __shfl_xor(s, 1);
      s += __shfl_xor(s, 2);
      s += __shfl_xor(s, 4);
      s += __shfl_xor(s, 8);
      lrow[r] += s;
    }
#pragma unroll
    for (int g = 0; g < 4; ++g)
#pragma unroll
      for (int r = 0; r < 4; ++r) Pw[(l4 * 4 + r) * 72 + g * 16 + l15] = f2b(pv[g][r]);
    s16x8 pf[2];
    pf[0] = *(const s16x8*)&Pw[l15 * 72 + l4 * 8];
    pf[1] = *(const s16x8*)&Pw[l15 * 72 + 32 + l4 * 8];
    __builtin_amdgcn_s_setprio(1);
#pragma unroll
    for (int n = 0; n < 8; ++n)
#pragma unroll
      for (int kk = 0; kk < 2; ++kk) {
        s16x8 vf = *(const s16x8*)&Vs[(n * 16 + l15) * 72 + kk * 32 + l4 * 8];
        accO[n] = __builtin_amdgcn_mfma_f32_16x16x32_bf16(pf[kk], vf, accO[n], 0, 0, 0);
      }
    __builtin_amdgcn_s_setprio(0);

    __syncthreads();
    if (kt < qt) {
      write_tile();
      __syncthreads();
    }
  }
  float inv[4];
#pragma unroll
  for (int r = 0; r < 4; ++r) inv[r] = 1.0f / lrow[r];
#pragma unroll
  for (int n = 0; n < 8; ++n)
#pragma unroll
    for (int r = 0; r < 4; ++r) {
      int s = q0 + w * 16 + l4 * 4 + r;
      ab[((size_t)(b * SEQ + s) * NH + h) * HD + n * 16 + l15] = f2b(accO[n][r] * inv[r]);
    }
}

// ---------------- launch -----------------------------------------------------------
extern "C" void kernel_launch(void* const* d_in, const int* in_sizes, int n_in,
                              void* d_out, int out_size, void* d_ws, size_t ws_size,
                              hipStream_t stream) {
  const float* x = (const float*)d_in[0];
  const float* wq = (const float*)d_in[1];
  const float* wk = (const float*)d_in[2];
  const float* wv = (const float*)d_in[3];
  const float* wo = (const float*)d_in[4];
  const float* fcos = (const float*)d_in[7];
  const float* fsin = (const float*)d_in[8];
  float* out = (float*)d_out;

  unsigned short* ws = (unsigned short*)d_ws;
  unsigned short* xb  = ws;                    // 16.78M el
  unsigned short* wqT = ws + 16777216;         // 16.78M
  unsigned short* wkT = ws + 33554432;         // 4.19M (contiguous with wvT -> wkvT)
  unsigned short* wvT = ws + 37748736;         // 4.19M
  unsigned short* woT = ws + 41943040;         // 16.78M
  unsigned short* qb  = ws + 58720256;         // 16.78M
  unsigned short* kvb = ws + 75497472;         // 8.39M  (k cols 0-1023 | v cols 1024-2047)
  unsigned short* vtb = ws + 83886080;         // 4.19M
  unsigned short* ab  = ws + 88080384;         // 16.78M

  convert_f32_bf16<<<(4194304 + 255) / 256, 256, 0, stream>>>(x, xb, 4194304);
  tconv<<<dim3(128, 128), 256, 0, stream>>>(wq, wqT, 4096);
  tconv<<<dim3(128, 32), 256, 0, stream>>>(wk, wkT, 1024);
  tconv<<<dim3(128, 32), 256, 0, stream>>>(wv, wvT, 1024);
  tconv<<<dim3(128, 128), 256, 0, stream>>>(wo, woT, 4096);

  gemm256<unsigned short><<<dim3(16, 16), 512, 0, stream>>>(xb, wqT, qb, MTOK, 4096, 4096);
  // merged k|v projection: BT = [wkT ; wvT] contiguous rows, N=2048, 512 blocks
  gemm_bt<unsigned short><<<dim3(32, 16), 256, 0, stream>>>(xb, wkT, kvb, MTOK, 2048, 4096);

  rope_k<<<(2097152 + 255) / 256, 256, 0, stream>>>(qb, fcos, fsin, 5, 2097152);
  rope_kv<<<(524288 + 255) / 256, 256, 0, stream>>>(kvb, fcos, fsin, 524288);

  vtrans<<<dim3(64, 4, 16), 256, 0, stream>>>(kvb, vtb);

  attn_kernel<<<2048, 256, 0, stream>>>(qb, kvb, vtb, ab);

  gemm256<float><<<dim3(16, 16), 512, 0, stream>>>(ab, woT, out, MTOK, 4096, 4096);
}